// Round 1
// 350.186 us; speedup vs baseline: 1.0132x; 1.0132x over previous
//
#include <hip/hip_runtime.h>

// Problem constants
#define B_    8
#define C_    128
#define H_    128
#define W_    128
#define NH    31              // (128-8)/4+1
#define NPB   (NH*NH)         // 961 patches per batch
#define NPAT  (B_*NPB)        // 7688
#define HW_   (H_*W_)
#define CHW_  (C_*HW_)
#define WS_BYTES ((size_t)NPAT * 8192 * 2)   // bf16 z per patch: 125,960,192 B

typedef float v4f __attribute__((ext_vector_type(4)));
typedef short v8s __attribute__((ext_vector_type(8)));

__device__ __forceinline__ unsigned short f2bf(float f) {
    unsigned int u = __builtin_bit_cast(unsigned int, f);
    u += 0x7FFFu + ((u >> 16) & 1u);   // RNE
    return (unsigned short)(u >> 16);
}
__device__ __forceinline__ float bflo(unsigned int d) {
    return __builtin_bit_cast(float, d << 16);
}
__device__ __forceinline__ float bfhi(unsigned int d) {
    return __builtin_bit_cast(float, d & 0xFFFF0000u);
}

// ============================= PASS 1 =====================================
// Per-patch attention; z written (normalized, bf16) to ws[p][c][t], coalesced.
// LDS 43264 B -> 3 blocks/CU. Repack buffer [128][70] u16 overlays sQ/sVT
// region after phase-2 reads complete.  (UNCHANGED this round.)

__global__ __launch_bounds__(512, 6)
void patch_attn_ws(const float* __restrict__ q,
                   const float* __restrict__ k,
                   const float* __restrict__ v,
                   unsigned short* __restrict__ ws)
{
    __shared__ __align__(16) unsigned char lds[43264];
    unsigned short* sQ   = (unsigned short*)(lds);
    unsigned short* sK   = (unsigned short*)(lds + 16384);
    unsigned short* sVT  = (unsigned short*)(lds);
    unsigned short* sP   = (unsigned short*)(lds + 32768);
    float*          sRedM= (float*)(lds + 40960);
    float*          sRedL= (float*)(lds + 41984);
    float*          sInv = (float*)(lds + 43008);
    unsigned short* sRep = (unsigned short*)(lds);          // [128][70] after B4

    const int tid  = threadIdx.x;
    const int lane = tid & 63;
    const int wid  = tid >> 6;
    const int l15  = lane & 15;
    const int quad = lane >> 4;

    // batch-per-XCD swizzle
    const int p   = (blockIdx.x & 7) * NPB + (blockIdx.x >> 3);
    const int b   = p / NPB;
    const int rem = p - b * NPB;
    const int ph  = rem / NH;
    const int pw  = rem - ph * NH;
    const int h0  = ph * 4, w0 = pw * 4;
    const int baseB = b * CHW_;

    // ---- global loads ----
    float4 rq[4], rk[4], rv[4];
    int cA[4], tA[4];
    #pragma unroll
    for (int g = 0; g < 4; ++g) {
        int flat4 = tid + g * 512;
        int jj = flat4 & 1;
        int i  = (flat4 >> 1) & 7;
        int c  = flat4 >> 4;
        int off = baseB + c * HW_ + (h0 + i) * W_ + (w0 + jj * 4);
        rq[g] = *(const float4*)(q + off);
        rk[g] = *(const float4*)(k + off);
        rv[g] = *(const float4*)(v + off);
        cA[g] = c;
        tA[g] = i * 8 + jj * 4;
    }
    #pragma unroll
    for (int g = 0; g < 4; ++g) {
        const float* fq = (const float*)&rq[g];
        const float* fk = (const float*)&rk[g];
        int c = cA[g];
        #pragma unroll
        for (int d = 0; d < 4; ++d) {
            int t = tA[g] + d;
            int idx = t * 128 + ((((c >> 3) ^ (t & 15)) << 3) | (c & 7));
            sQ[idx] = f2bf(fq[d]);
            sK[idx] = f2bf(fk[d]);
        }
    }
    __syncthreads();   // B1

    // ---- phase 1: S = Q K^T ----
    const float scale = 0.08838834764831845f;
    const int nt  = wid & 3;
    const int mt0 = wid >> 2;

    v4f accT[2];
    #pragma unroll
    for (int ti = 0; ti < 2; ++ti) {
        int mt = mt0 + ti * 2;
        v4f acc = {0.f, 0.f, 0.f, 0.f};
        int rowA = mt * 16 + l15;
        int rowB = nt * 16 + l15;
        #pragma unroll
        for (int kk = 0; kk < 4; ++kk) {
            int gph = (kk * 4 + quad) ^ l15;
            v8s a  = *(const v8s*)(&sQ[rowA * 128 + gph * 8]);
            v8s bb = *(const v8s*)(&sK[rowB * 128 + gph * 8]);
            acc = __builtin_amdgcn_mfma_f32_16x16x32_bf16(a, bb, acc, 0, 0, 0);
        }
        #pragma unroll
        for (int r = 0; r < 4; ++r) acc[r] *= scale;
        accT[ti] = acc;
    }

    // in-register partial softmax over 16 columns
    float4 mloc[2], eV[2];
    #pragma unroll
    for (int ti = 0; ti < 2; ++ti) {
        float4 m;
        #pragma unroll
        for (int r = 0; r < 4; ++r) m[r] = accT[ti][r];
        #pragma unroll
        for (int mask = 1; mask <= 8; mask <<= 1)
            #pragma unroll
            for (int r = 0; r < 4; ++r) m[r] = fmaxf(m[r], __shfl_xor(m[r], mask));
        float4 e, l;
        #pragma unroll
        for (int r = 0; r < 4; ++r) { e[r] = __expf(accT[ti][r] - m[r]); l[r] = e[r]; }
        #pragma unroll
        for (int mask = 1; mask <= 8; mask <<= 1)
            #pragma unroll
            for (int r = 0; r < 4; ++r) l[r] += __shfl_xor(l[r], mask);
        mloc[ti] = m; eV[ti] = e;
        if (l15 == 0) {
            int tb = (mt0 + ti * 2) * 16 + quad * 4;
            #pragma unroll
            for (int r = 0; r < 4; ++r) {
                sRedM[nt * 64 + tb + r] = m[r];
                sRedL[nt * 64 + tb + r] = l[r];
            }
        }
    }
    __syncthreads();   // B2

    // ---- stage V -> sVT[c][s] ----
    #pragma unroll
    for (int g = 0; g < 4; ++g) {
        const float* fv = (const float*)&rv[g];
        unsigned short tmp[4];
        #pragma unroll
        for (int d = 0; d < 4; ++d) tmp[d] = f2bf(fv[d]);
        int c = cA[g], s0 = tA[g];
        int idx = c * 64 + ((((s0 >> 3) ^ (c & 7)) << 3) | (s0 & 7));
        *(uint2*)(&sVT[idx]) = *(const uint2*)tmp;
    }

    // ---- finish softmax ----
    #pragma unroll
    for (int ti = 0; ti < 2; ++ti) {
        int tb = (mt0 + ti * 2) * 16 + quad * 4;
        float4 Mv[4], Lv[4];
        #pragma unroll
        for (int n2 = 0; n2 < 4; ++n2) {
            Mv[n2] = *(const float4*)(&sRedM[n2 * 64 + tb]);
            Lv[n2] = *(const float4*)(&sRedL[n2 * 64 + tb]);
        }
        float4 M = Mv[0], L;
        #pragma unroll
        for (int n2 = 1; n2 < 4; ++n2)
            #pragma unroll
            for (int r = 0; r < 4; ++r) M[r] = fmaxf(M[r], Mv[n2][r]);
        #pragma unroll
        for (int r = 0; r < 4; ++r) L[r] = 0.f;
        #pragma unroll
        for (int n2 = 0; n2 < 4; ++n2)
            #pragma unroll
            for (int r = 0; r < 4; ++r) L[r] += Lv[n2][r] * __expf(Mv[n2][r] - M[r]);
        #pragma unroll
        for (int r = 0; r < 4; ++r) {
            float pv = eV[ti][r] * __expf(mloc[ti][r] - M[r]);
            int t = tb + r;
            int s = nt * 16 + l15;
            sP[t * 64 + ((((s >> 3) ^ (t & 7)) << 3) | (s & 7))] = f2bf(pv);
        }
        if (nt == 0 && l15 == 0) {
            #pragma unroll
            for (int r = 0; r < 4; ++r) sInv[tb + r] = 1.0f / L[r];
        }
    }
    __syncthreads();   // B3

    // ---- phase 2: Z^T = V^T * P^T ----
    v4f z[4];
    #pragma unroll
    for (int n2 = 0; n2 < 4; ++n2) z[n2] = (v4f){0.f, 0.f, 0.f, 0.f};
    const int crow = wid * 16 + l15;
    #pragma unroll
    for (int kk = 0; kk < 2; ++kk) {
        int gph = (kk * 4 + quad) ^ (l15 & 7);
        v8s a = *(const v8s*)(&sVT[crow * 64 + gph * 8]);
        #pragma unroll
        for (int n2 = 0; n2 < 4; ++n2) {
            int trow = n2 * 16 + l15;
            v8s bb = *(const v8s*)(&sP[trow * 64 + gph * 8]);
            z[n2] = __builtin_amdgcn_mfma_f32_16x16x32_bf16(a, bb, z[n2], 0, 0, 0);
        }
    }
    __syncthreads();   // B4: phase-2 LDS reads done; sQ/sVT region reusable

    // ---- epilogue: repack via LDS, coalesced bf16 store to ws[p][c][t] ----
    #pragma unroll
    for (int n2 = 0; n2 < 4; ++n2) {
        int t = n2 * 16 + l15;
        float inv = sInv[t];
        #pragma unroll
        for (int r = 0; r < 4; ++r) {
            int c = wid * 16 + quad * 4 + r;
            sRep[c * 70 + t] = f2bf(z[n2][r] * inv);
        }
    }
    __syncthreads();   // B5
    {
        int c = tid >> 2, tseg = tid & 3;
        const unsigned short* src = &sRep[c * 70 + tseg * 16];
        uint2 d0 = *(const uint2*)(src);
        uint2 d1 = *(const uint2*)(src + 4);
        uint2 d2 = *(const uint2*)(src + 8);
        uint2 d3 = *(const uint2*)(src + 12);
        unsigned short* dst = ws + (size_t)p * 8192 + c * 64 + tseg * 16;
        uint4 w0v; w0v.x = d0.x; w0v.y = d0.y; w0v.z = d1.x; w0v.w = d1.y;
        uint4 w1v; w1v.x = d2.x; w1v.y = d2.y; w1v.z = d3.x; w1v.w = d3.y;
        ((uint4*)dst)[0] = w0v;
        ((uint4*)dst)[1] = w1v;
    }
}

// ============================= PASS 2 =====================================
// LDS-staged gather-merge.  Block = (b, hq, 8-channel group) covering output
// rows h = 4hq..4hq+3, all 128 w, 8 channels.
//
// Old version: per-instruction 64-lane address divergence (lanes stride 16 KB
// across patches) -> ~64 transactions per load instr -> issue-bound, ~160 us.
// New version: stage the needed 31 patches x 8 ch x 64 B half-lines (31.7 KB)
// into LDS with MONOTONE sector-dense loads (consecutive lanes read
// consecutive 16 B chunks; each wave instr covers 16 distinct 64 B sectors),
// then combine out of LDS.  Guard slots 0 and 32 are zeroed so boundary
// patches need no per-pixel predication.
//
// LDS layout: sA/sB [33 slots][264 u16]; slot stride 528 B (16B-aligned,
// 132 dw == 4 mod 32 banks -> <=4-way conflict on 8 B combine reads).
// slot s holds patch pw = s-1;  sA = th 0..3 half (ph = hq),
// sB = th 4..7 half (ph = hq-1), stored at local t' = t - 32.

#define MSLOT 264                      // u16 per slot (8c x 32t + 4 pad)
#define MARR  (33 * MSLOT)             // u16 per array

__global__ __launch_bounds__(256, 4)
void merge_kernel(const unsigned short* __restrict__ ws,
                  float* __restrict__ out)
{
    __shared__ __align__(16) unsigned short sM[2 * MARR];   // 34848 B
    unsigned short* sA = sM;
    unsigned short* sB = sM + MARR;

    const int tid  = threadIdx.x;
    const int b    = blockIdx.x & 7;          // batch-per-XCD
    const int rest = blockIdx.x >> 3;         // 0..511
    const int hq   = rest >> 4;               // 0..31 : h = 4hq + hr
    const int cg   = rest & 15;

    // ---- zero guard slots (0 and 32 of each array): 4 slots x 33 uint4 ----
    if (tid < 132) {
        int target = tid / 33;                // 0..3 : A0, A32, B0, B32
        int j      = tid - target * 33;       // uint4 index within slot
        unsigned short* base = ((target < 2) ? sA : sB)
                             + ((target & 1) ? 32 * MSLOT : 0);
        uint4 zz; zz.x = 0u; zz.y = 0u; zz.z = 0u; zz.w = 0u;
        *(uint4*)(base + j * 8) = zz;
    }

    // ---- stage: 2 x 31 pw x 8 c x 64 B = 31744 B, 16 B per lane-load ----
    const int aValid = (hq <= 30);
    const int bValid = (hq >= 1);
    const int hqB = bValid ? (hq - 1) : 0;    // clamped (loads predicated off)
    const size_t rowA = (size_t)(b * NPB + hq  * NH) * 8192;   // + pw*8192 + c*64
    const size_t rowB = (size_t)(b * NPB + hqB * NH) * 8192;

    #pragma unroll
    for (int it = 0; it < 8; ++it) {
        int flat = tid + it * 256;            // 0..2047 ; 1984 used
        if (flat < 1984) {
            int half = (flat >= 992);
            int fl   = flat - (half ? 992 : 0);
            int seg  = fl >> 2;               // 0..247
            int sub  = fl & 3;                // 16 B chunk within 64 B half-line
            int pw   = seg >> 3;              // 0..30
            int csub = seg & 7;
            const unsigned short* src = ws
                + (half ? rowB : rowA)
                + (size_t)pw * 8192
                + (size_t)(cg * 8 + csub) * 64
                + (half ? 32 : 0)             // th 4..7 half
                + sub * 8;
            int valid = half ? bValid : aValid;
            uint4 val;
            if (valid) {
                val = *(const uint4*)src;
            } else {
                val.x = 0u; val.y = 0u; val.z = 0u; val.w = 0u;
            }
            unsigned short* dst = (half ? sB : sA)
                + (pw + 1) * MSLOT + csub * 32 + sub * 8;
            *(uint4*)dst = val;
        }
    }
    __syncthreads();

    // ---- combine: out(4hq+hr, 4l+j, c) = A[l][j] + A[l-1][j+4]
    //                                    + B[l][j] + B[l-1][j+4] ----
    const int l    = tid & 31;                // w quad : w = 4l..4l+3
    const int csub = tid >> 5;                // 0..7
    const int c    = cg * 8 + csub;

    float* op = out + b * CHW_ + c * HW_ + (hq * 4) * W_ + l * 4;
    #pragma unroll
    for (int hr = 0; hr < 4; ++hr) {
        int baseL = (l + 1) * MSLOT + csub * 32 + hr * 8;      // own patch, tw 0..3
        int baseP = l       * MSLOT + csub * 32 + hr * 8 + 4;  // left patch, tw 4..7
        uint2 aL = *(const uint2*)(sA + baseL);
        uint2 aP = *(const uint2*)(sA + baseP);
        uint2 bL = *(const uint2*)(sB + baseL);
        uint2 bP = *(const uint2*)(sB + baseP);
        float4 r;
        r.x = bflo(aL.x) + bflo(aP.x) + bflo(bL.x) + bflo(bP.x);
        r.y = bfhi(aL.x) + bfhi(aP.x) + bfhi(bL.x) + bfhi(bP.x);
        r.z = bflo(aL.y) + bflo(aP.y) + bflo(bL.y) + bflo(bP.y);
        r.w = bfhi(aL.y) + bfhi(aP.y) + bfhi(bL.y) + bfhi(bP.y);
        *(float4*)(op + hr * W_) = r;
    }
}

// ========================= FALLBACK (atomic) ==============================

__global__ __launch_bounds__(512, 6)
void patch_attn_atomic(const float* __restrict__ q,
                       const float* __restrict__ k,
                       const float* __restrict__ v,
                       float* __restrict__ out)
{
    __shared__ __align__(16) unsigned char lds[43264];
    unsigned short* sQ   = (unsigned short*)(lds);
    unsigned short* sK   = (unsigned short*)(lds + 16384);
    unsigned short* sVT  = (unsigned short*)(lds);
    unsigned short* sP   = (unsigned short*)(lds + 32768);
    float*          sRedM= (float*)(lds + 40960);
    float*          sRedL= (float*)(lds + 41984);
    float*          sInv = (float*)(lds + 43008);

    const int tid  = threadIdx.x;
    const int lane = tid & 63;
    const int wid  = tid >> 6;
    const int l15  = lane & 15;
    const int quad = lane >> 4;

    const int p   = (blockIdx.x & 7) * NPB + (blockIdx.x >> 3);
    const int b   = p / NPB;
    const int rem = p - b * NPB;
    const int ph  = rem / NH;
    const int pw  = rem - ph * NH;
    const int h0  = ph * 4, w0 = pw * 4;
    const int baseB = b * CHW_;

    float4 rq[4], rk[4], rv[4];
    int cA[4], tA[4];
    #pragma unroll
    for (int g = 0; g < 4; ++g) {
        int flat4 = tid + g * 512;
        int jj = flat4 & 1;
        int i  = (flat4 >> 1) & 7;
        int c  = flat4 >> 4;
        int off = baseB + c * HW_ + (h0 + i) * W_ + (w0 + jj * 4);
        rq[g] = *(const float4*)(q + off);
        rk[g] = *(const float4*)(k + off);
        rv[g] = *(const float4*)(v + off);
        cA[g] = c;
        tA[g] = i * 8 + jj * 4;
    }
    #pragma unroll
    for (int g = 0; g < 4; ++g) {
        const float* fq = (const float*)&rq[g];
        const float* fk = (const float*)&rk[g];
        int c = cA[g];
        #pragma unroll
        for (int d = 0; d < 4; ++d) {
            int t = tA[g] + d;
            int idx = t * 128 + ((((c >> 3) ^ (t & 15)) << 3) | (c & 7));
            sQ[idx] = f2bf(fq[d]);
            sK[idx] = f2bf(fk[d]);
        }
    }
    __syncthreads();

    const float scale = 0.08838834764831845f;
    const int nt  = wid & 3;
    const int mt0 = wid >> 2;

    v4f accT[2];
    #pragma unroll
    for (int ti = 0; ti < 2; ++ti) {
        int mt = mt0 + ti * 2;
        v4f acc = {0.f, 0.f, 0.f, 0.f};
        int rowA = mt * 16 + l15;
        int rowB = nt * 16 + l15;
        #pragma unroll
        for (int kk = 0; kk < 4; ++kk) {
            int gph = (kk * 4 + quad) ^ l15;
            v8s a  = *(const v8s*)(&sQ[rowA * 128 + gph * 8]);
            v8s bb = *(const v8s*)(&sK[rowB * 128 + gph * 8]);
            acc = __builtin_amdgcn_mfma_f32_16x16x32_bf16(a, bb, acc, 0, 0, 0);
        }
        #pragma unroll
        for (int r = 0; r < 4; ++r) acc[r] *= scale;
        accT[ti] = acc;
    }

    float4 mloc[2], eV[2];
    #pragma unroll
    for (int ti = 0; ti < 2; ++ti) {
        float4 m;
        #pragma unroll
        for (int r = 0; r < 4; ++r) m[r] = accT[ti][r];
        #pragma unroll
        for (int mask = 1; mask <= 8; mask <<= 1)
            #pragma unroll
            for (int r = 0; r < 4; ++r) m[r] = fmaxf(m[r], __shfl_xor(m[r], mask));
        float4 e, l;
        #pragma unroll
        for (int r = 0; r < 4; ++r) { e[r] = __expf(accT[ti][r] - m[r]); l[r] = e[r]; }
        #pragma unroll
        for (int mask = 1; mask <= 8; mask <<= 1)
            #pragma unroll
            for (int r = 0; r < 4; ++r) l[r] += __shfl_xor(l[r], mask);
        mloc[ti] = m; eV[ti] = e;
        if (l15 == 0) {
            int tb = (mt0 + ti * 2) * 16 + quad * 4;
            #pragma unroll
            for (int r = 0; r < 4; ++r) {
                sRedM[nt * 64 + tb + r] = m[r];
                sRedL[nt * 64 + tb + r] = l[r];
            }
        }
    }
    __syncthreads();

    #pragma unroll
    for (int g = 0; g < 4; ++g) {
        const float* fv = (const float*)&rv[g];
        unsigned short tmp[4];
        #pragma unroll
        for (int d = 0; d < 4; ++d) tmp[d] = f2bf(fv[d]);
        int c = cA[g], s0 = tA[g];
        int idx = c * 64 + ((((s0 >> 3) ^ (c & 7)) << 3) | (s0 & 7));
        *(uint2*)(&sVT[idx]) = *(const uint2*)tmp;
    }

    #pragma unroll
    for (int ti = 0; ti < 2; ++ti) {
        int tb = (mt0 + ti * 2) * 16 + quad * 4;
        float4 Mv[4], Lv[4];
        #pragma unroll
        for (int n2 = 0; n2 < 4; ++n2) {
            Mv[n2] = *(const float4*)(&sRedM[n2 * 64 + tb]);
            Lv[n2] = *(const float4*)(&sRedL[n2 * 64 + tb]);
        }
        float4 M = Mv[0], L;
        #pragma unroll
        for (int n2 = 1; n2 < 4; ++n2)
            #pragma unroll
            for (int r = 0; r < 4; ++r) M[r] = fmaxf(M[r], Mv[n2][r]);
        #pragma unroll
        for (int r = 0; r < 4; ++r) L[r] = 0.f;
        #pragma unroll
        for (int n2 = 0; n2 < 4; ++n2)
            #pragma unroll
            for (int r = 0; r < 4; ++r) L[r] += Lv[n2][r] * __expf(Mv[n2][r] - M[r]);
        #pragma unroll
        for (int r = 0; r < 4; ++r) {
            float pv = eV[ti][r] * __expf(mloc[ti][r] - M[r]);
            int t = tb + r;
            int s = nt * 16 + l15;
            sP[t * 64 + ((((s >> 3) ^ (t & 7)) << 3) | (s & 7))] = f2bf(pv);
        }
        if (nt == 0 && l15 == 0) {
            #pragma unroll
            for (int r = 0; r < 4; ++r) sInv[tb + r] = 1.0f / L[r];
        }
    }
    __syncthreads();

    v4f z[4];
    #pragma unroll
    for (int n2 = 0; n2 < 4; ++n2) z[n2] = (v4f){0.f, 0.f, 0.f, 0.f};
    const int crow = wid * 16 + l15;
    #pragma unroll
    for (int kk = 0; kk < 2; ++kk) {
        int gph = (kk * 4 + quad) ^ (l15 & 7);
        v8s a = *(const v8s*)(&sVT[crow * 64 + gph * 8]);
        #pragma unroll
        for (int n2 = 0; n2 < 4; ++n2) {
            int trow = n2 * 16 + l15;
            v8s bb = *(const v8s*)(&sP[trow * 64 + gph * 8]);
            z[n2] = __builtin_amdgcn_mfma_f32_16x16x32_bf16(a, bb, z[n2], 0, 0, 0);
        }
    }

    #pragma unroll
    for (int n2 = 0; n2 < 4; ++n2) {
        int t = n2 * 16 + l15;
        float inv = sInv[t];
        int base2 = baseB + (h0 + (t >> 3)) * W_ + (w0 + (t & 7));
        #pragma unroll
        for (int r = 0; r < 4; ++r) {
            int c = wid * 16 + quad * 4 + r;
            unsafeAtomicAdd(out + base2 + c * HW_, z[n2][r] * inv);
        }
    }
}

extern "C" void kernel_launch(void* const* d_in, const int* in_sizes, int n_in,
                              void* d_out, int out_size, void* d_ws, size_t ws_size,
                              hipStream_t stream) {
    const float* q = (const float*)d_in[0];
    const float* k = (const float*)d_in[1];
    const float* v = (const float*)d_in[2];
    float* out = (float*)d_out;

    if (ws_size >= WS_BYTES) {
        unsigned short* ws = (unsigned short*)d_ws;
        patch_attn_ws<<<NPAT, 512, 0, stream>>>(q, k, v, ws);
        merge_kernel<<<8 * 32 * 16, 256, 0, stream>>>(ws, out);
    } else {
        hipMemsetAsync(out, 0, (size_t)out_size * sizeof(float), stream);
        patch_attn_atomic<<<NPAT, 512, 0, stream>>>(q, k, v, out);
    }
}

// Round 2
// 347.357 us; speedup vs baseline: 1.0215x; 1.0081x over previous
//
#include <hip/hip_runtime.h>

// Problem constants
#define B_    8
#define C_    128
#define H_    128
#define W_    128
#define NH    31              // (128-8)/4+1
#define NPB   (NH*NH)         // 961 patches per batch
#define NPAT  (B_*NPB)        // 7688
#define HW_   (H_*W_)
#define CHW_  (C_*HW_)
#define WS_BYTES ((size_t)NPAT * 8192 * 2)   // bf16 z per patch: 125,960,192 B

typedef float v4f __attribute__((ext_vector_type(4)));
typedef short v8s __attribute__((ext_vector_type(8)));

__device__ __forceinline__ unsigned short f2bf(float f) {
    unsigned int u = __builtin_bit_cast(unsigned int, f);
    u += 0x7FFFu + ((u >> 16) & 1u);   // RNE
    return (unsigned short)(u >> 16);
}
__device__ __forceinline__ unsigned int pack2bf(float lo, float hi) {
    return (unsigned int)f2bf(lo) | ((unsigned int)f2bf(hi) << 16);
}
__device__ __forceinline__ float bflo(unsigned int d) {
    return __builtin_bit_cast(float, d << 16);
}
__device__ __forceinline__ float bfhi(unsigned int d) {
    return __builtin_bit_cast(float, d & 0xFFFF0000u);
}

// ============================= PASS 1 =====================================
// v2: 256-thread / 4-wave blocks, one patch per block.
// Swapped QK^T: D[s][t] = mfma(K_frag, Q_frag) so each lane holds the FULL
// s-range (16 regs) for one t-column -> softmax is 15 local ops + 2 shfl_xor
// (quad exchange). P is pre-normalized (x 1/L) before the bf16 pack, so
// phase-2 output is final: sRedM/sRedL/sInv and their barrier are gone.
// Staging packs adjacent-c pairs into u32 LDS writes (halves LDS write instrs).
// LDS 32768 B: sQ[0,16K) sK[16K,32K); sVT overlays sQ, sP overlays sK[0,8K),
// repack sRep[128][66] overlays base after phase-2 reads.  4 blocks/CU.

__global__ __launch_bounds__(256, 4)
void patch_attn_ws(const float* __restrict__ q,
                   const float* __restrict__ k,
                   const float* __restrict__ v,
                   unsigned short* __restrict__ ws)
{
    __shared__ __align__(16) unsigned char lds[32768];
    unsigned short* sQ  = (unsigned short*)(lds);            // [64 t][128 c]
    unsigned short* sK  = (unsigned short*)(lds + 16384);    // [64 s][128 c]
    unsigned short* sVT = (unsigned short*)(lds);            // [128 c][64 s]
    unsigned short* sP  = (unsigned short*)(lds + 16384);    // [64 t][64 s]
    unsigned short* sRep= (unsigned short*)(lds);            // [128 c][66]

    const int tid  = threadIdx.x;
    const int lane = tid & 63;
    const int l15  = lane & 15;
    const int quad = lane >> 4;
    const int wid  = tid >> 6;            // 0..3

    // batch-per-XCD swizzle
    const int p   = (blockIdx.x & 7) * NPB + (blockIdx.x >> 3);
    const int b   = p / NPB;
    const int rem = p - b * NPB;
    const int ph  = rem / NH;
    const int pw  = rem - ph * NH;
    const int h0  = ph * 4, w0 = pw * 4;
    const int baseB = b * CHW_;

    // ---- stage Q,K: adjacent-c pairs -> packed u32 LDS writes ----
    {
        float4 qa[4], qb[4], ka[4], kb[4];
        int c0A[4], tA[4];
        #pragma unroll
        for (int g = 0; g < 4; ++g) {
            int flat2 = tid + g * 256;        // 0..1023
            int jj = flat2 & 1;
            int i  = (flat2 >> 1) & 7;
            int cp = flat2 >> 4;              // 0..63
            int c0 = cp * 2;
            int off0 = baseB + c0 * HW_ + (h0 + i) * W_ + (w0 + jj * 4);
            qa[g] = *(const float4*)(q + off0);
            qb[g] = *(const float4*)(q + off0 + HW_);
            ka[g] = *(const float4*)(k + off0);
            kb[g] = *(const float4*)(k + off0 + HW_);
            c0A[g] = c0;
            tA[g]  = i * 8 + jj * 4;
        }
        #pragma unroll
        for (int g = 0; g < 4; ++g) {
            const float* fqa = (const float*)&qa[g];
            const float* fqb = (const float*)&qb[g];
            const float* fka = (const float*)&ka[g];
            const float* fkb = (const float*)&kb[g];
            int c0 = c0A[g];
            #pragma unroll
            for (int d = 0; d < 4; ++d) {
                int t = tA[g] + d;
                int chunk = (c0 >> 3) ^ (t & 15);
                int pos = t * 128 + chunk * 8 + (c0 & 7);
                *(unsigned int*)&sQ[pos] = pack2bf(fqa[d], fqb[d]);
                *(unsigned int*)&sK[pos] = pack2bf(fka[d], fkb[d]);
            }
        }
    }
    __syncthreads();   // B1

    // ---- phase 1: D[s][t] = K Q^T  (swapped operands) ----
    v4f acc0, acc1, acc2, acc3;
    acc0 = acc1 = acc2 = acc3 = (v4f){0.f, 0.f, 0.f, 0.f};
    const int rowT = wid * 16 + l15;
    #pragma unroll
    for (int kk = 0; kk < 4; ++kk) {
        int gph = (kk * 4 + quad) ^ l15;
        v8s bq = *(const v8s*)(&sQ[rowT * 128 + gph * 8]);
        v8s a0 = *(const v8s*)(&sK[( 0 + l15) * 128 + gph * 8]);
        v8s a1 = *(const v8s*)(&sK[(16 + l15) * 128 + gph * 8]);
        v8s a2 = *(const v8s*)(&sK[(32 + l15) * 128 + gph * 8]);
        v8s a3 = *(const v8s*)(&sK[(48 + l15) * 128 + gph * 8]);
        acc0 = __builtin_amdgcn_mfma_f32_16x16x32_bf16(a0, bq, acc0, 0, 0, 0);
        acc1 = __builtin_amdgcn_mfma_f32_16x16x32_bf16(a1, bq, acc1, 0, 0, 0);
        acc2 = __builtin_amdgcn_mfma_f32_16x16x32_bf16(a2, bq, acc2, 0, 0, 0);
        acc3 = __builtin_amdgcn_mfma_f32_16x16x32_bf16(a3, bq, acc3, 0, 0, 0);
    }

    // ---- issue V loads early (latency hidden under softmax) ----
    float4 rv[8];
    int cV[8], sV[8];
    #pragma unroll
    for (int g = 0; g < 8; ++g) {
        int flat4 = tid + g * 256;            // 0..2047
        int jj = flat4 & 1;
        int i  = (flat4 >> 1) & 7;
        int c  = flat4 >> 4;                  // 0..127
        rv[g] = *(const float4*)(v + baseB + c * HW_ + (h0 + i) * W_ + (w0 + jj * 4));
        cV[g] = c;
        sV[g] = i * 8 + jj * 4;
    }

    // ---- softmax over s (lane-local 16 values + quad exchange) ----
    const float scale = 0.08838834764831845f;
    float e0[4], e1[4], e2[4], e3[4];
    unsigned int pPk[8];                       // packed P, 4 m-tiles x uint2
    {
        float mx = -1e30f;
        #pragma unroll
        for (int r = 0; r < 4; ++r) {
            e0[r] = acc0[r] * scale; mx = fmaxf(mx, e0[r]);
            e1[r] = acc1[r] * scale; mx = fmaxf(mx, e1[r]);
            e2[r] = acc2[r] * scale; mx = fmaxf(mx, e2[r]);
            e3[r] = acc3[r] * scale; mx = fmaxf(mx, e3[r]);
        }
        mx = fmaxf(mx, __shfl_xor(mx, 16));
        mx = fmaxf(mx, __shfl_xor(mx, 32));
        float sum = 0.f;
        #pragma unroll
        for (int r = 0; r < 4; ++r) {
            e0[r] = __expf(e0[r] - mx); sum += e0[r];
            e1[r] = __expf(e1[r] - mx); sum += e1[r];
            e2[r] = __expf(e2[r] - mx); sum += e2[r];
            e3[r] = __expf(e3[r] - mx); sum += e3[r];
        }
        sum += __shfl_xor(sum, 16);
        sum += __shfl_xor(sum, 32);
        float inv = 1.0f / sum;
        pPk[0] = pack2bf(e0[0] * inv, e0[1] * inv);
        pPk[1] = pack2bf(e0[2] * inv, e0[3] * inv);
        pPk[2] = pack2bf(e1[0] * inv, e1[1] * inv);
        pPk[3] = pack2bf(e1[2] * inv, e1[3] * inv);
        pPk[4] = pack2bf(e2[0] * inv, e2[1] * inv);
        pPk[5] = pack2bf(e2[2] * inv, e2[3] * inv);
        pPk[6] = pack2bf(e3[0] * inv, e3[1] * inv);
        pPk[7] = pack2bf(e3[2] * inv, e3[3] * inv);
    }
    __syncthreads();   // B2: all phase-1 LDS reads done; sQ/sK reusable

    // ---- stage V -> sVT[c][s] (overlays sQ) ----
    #pragma unroll
    for (int g = 0; g < 8; ++g) {
        const float* fv = (const float*)&rv[g];
        int c = cV[g], s0 = sV[g];
        unsigned int w0p = pack2bf(fv[0], fv[1]);
        unsigned int w1p = pack2bf(fv[2], fv[3]);
        int idx = c * 64 + ((((s0 >> 3) ^ (c & 7)) << 3) | (s0 & 7));
        uint2 val; val.x = w0p; val.y = w1p;
        *(uint2*)(&sVT[idx]) = val;
    }

    // ---- write P -> sP[t][s] (overlays sK head), normalized bf16 ----
    {
        const int t = rowT;
        const int qh = quad >> 1, ql = quad & 1;
        #pragma unroll
        for (int m = 0; m < 4; ++m) {
            int chunk = (m * 2 + qh) ^ (t & 7);
            uint2 val;
            val.x = pPk[m * 2];
            val.y = pPk[m * 2 + 1];
            *(uint2*)(&sP[t * 64 + chunk * 8 + ql * 4]) = val;
        }
    }
    __syncthreads();   // B3

    // ---- phase 2: Z[c][t] = V^T P^T ----
    v4f z00, z01, z02, z03, z10, z11, z12, z13;
    z00 = z01 = z02 = z03 = (v4f){0.f, 0.f, 0.f, 0.f};
    z10 = z11 = z12 = z13 = (v4f){0.f, 0.f, 0.f, 0.f};
    #pragma unroll
    for (int kk = 0; kk < 2; ++kk) {
        int gph = (kk * 4 + quad) ^ (l15 & 7);
        v8s b0 = *(const v8s*)(&sP[( 0 + l15) * 64 + gph * 8]);
        v8s b1 = *(const v8s*)(&sP[(16 + l15) * 64 + gph * 8]);
        v8s b2 = *(const v8s*)(&sP[(32 + l15) * 64 + gph * 8]);
        v8s b3 = *(const v8s*)(&sP[(48 + l15) * 64 + gph * 8]);
        v8s aA = *(const v8s*)(&sVT[(wid * 32      + l15) * 64 + gph * 8]);
        v8s aB = *(const v8s*)(&sVT[(wid * 32 + 16 + l15) * 64 + gph * 8]);
        z00 = __builtin_amdgcn_mfma_f32_16x16x32_bf16(aA, b0, z00, 0, 0, 0);
        z01 = __builtin_amdgcn_mfma_f32_16x16x32_bf16(aA, b1, z01, 0, 0, 0);
        z02 = __builtin_amdgcn_mfma_f32_16x16x32_bf16(aA, b2, z02, 0, 0, 0);
        z03 = __builtin_amdgcn_mfma_f32_16x16x32_bf16(aA, b3, z03, 0, 0, 0);
        z10 = __builtin_amdgcn_mfma_f32_16x16x32_bf16(aB, b0, z10, 0, 0, 0);
        z11 = __builtin_amdgcn_mfma_f32_16x16x32_bf16(aB, b1, z11, 0, 0, 0);
        z12 = __builtin_amdgcn_mfma_f32_16x16x32_bf16(aB, b2, z12, 0, 0, 0);
        z13 = __builtin_amdgcn_mfma_f32_16x16x32_bf16(aB, b3, z13, 0, 0, 0);
    }
    __syncthreads();   // B4: phase-2 LDS reads done; whole LDS reusable

    // ---- repack z -> sRep[c][t] (pad 66 breaks bank alignment) ----
    {
        const int cb0 = wid * 32 + quad * 4;
        #pragma unroll
        for (int r = 0; r < 4; ++r) {
            int cA = cb0 + r, cB = cb0 + 16 + r;
            sRep[cA * 66 + ( 0 + l15)] = f2bf(z00[r]);
            sRep[cA * 66 + (16 + l15)] = f2bf(z01[r]);
            sRep[cA * 66 + (32 + l15)] = f2bf(z02[r]);
            sRep[cA * 66 + (48 + l15)] = f2bf(z03[r]);
            sRep[cB * 66 + ( 0 + l15)] = f2bf(z10[r]);
            sRep[cB * 66 + (16 + l15)] = f2bf(z11[r]);
            sRep[cB * 66 + (32 + l15)] = f2bf(z12[r]);
            sRep[cB * 66 + (48 + l15)] = f2bf(z13[r]);
        }
    }
    __syncthreads();   // B5

    // ---- coalesced bf16 store to ws[p][c][t] ----
    {
        int c = tid >> 1, th = tid & 1;
        const unsigned short* src = &sRep[c * 66 + th * 32];
        uint2 d0 = *(const uint2*)(src);
        uint2 d1 = *(const uint2*)(src + 4);
        uint2 d2 = *(const uint2*)(src + 8);
        uint2 d3 = *(const uint2*)(src + 12);
        uint2 d4 = *(const uint2*)(src + 16);
        uint2 d5 = *(const uint2*)(src + 20);
        uint2 d6 = *(const uint2*)(src + 24);
        uint2 d7 = *(const uint2*)(src + 28);
        unsigned short* dst = ws + (size_t)p * 8192 + c * 64 + th * 32;
        uint4 w0v; w0v.x = d0.x; w0v.y = d0.y; w0v.z = d1.x; w0v.w = d1.y;
        uint4 w1v; w1v.x = d2.x; w1v.y = d2.y; w1v.z = d3.x; w1v.w = d3.y;
        uint4 w2v; w2v.x = d4.x; w2v.y = d4.y; w2v.z = d5.x; w2v.w = d5.y;
        uint4 w3v; w3v.x = d6.x; w3v.y = d6.y; w3v.z = d7.x; w3v.w = d7.y;
        ((uint4*)dst)[0] = w0v;
        ((uint4*)dst)[1] = w1v;
        ((uint4*)dst)[2] = w2v;
        ((uint4*)dst)[3] = w3v;
    }
}

// ============================= PASS 2 =====================================
// LDS-staged gather-merge (unchanged from round 1).

#define MSLOT 264                      // u16 per slot (8c x 32t + 4 pad)
#define MARR  (33 * MSLOT)             // u16 per array

__global__ __launch_bounds__(256, 4)
void merge_kernel(const unsigned short* __restrict__ ws,
                  float* __restrict__ out)
{
    __shared__ __align__(16) unsigned short sM[2 * MARR];   // 34848 B
    unsigned short* sA = sM;
    unsigned short* sB = sM + MARR;

    const int tid  = threadIdx.x;
    const int b    = blockIdx.x & 7;          // batch-per-XCD
    const int rest = blockIdx.x >> 3;         // 0..511
    const int hq   = rest >> 4;               // 0..31 : h = 4hq + hr
    const int cg   = rest & 15;

    // ---- zero guard slots (0 and 32 of each array) ----
    if (tid < 132) {
        int target = tid / 33;                // 0..3 : A0, A32, B0, B32
        int j      = tid - target * 33;
        unsigned short* base = ((target < 2) ? sA : sB)
                             + ((target & 1) ? 32 * MSLOT : 0);
        uint4 zz; zz.x = 0u; zz.y = 0u; zz.z = 0u; zz.w = 0u;
        *(uint4*)(base + j * 8) = zz;
    }

    // ---- stage: 2 x 31 pw x 8 c x 64 B = 31744 B, 16 B per lane-load ----
    const int aValid = (hq <= 30);
    const int bValid = (hq >= 1);
    const int hqB = bValid ? (hq - 1) : 0;
    const size_t rowA = (size_t)(b * NPB + hq  * NH) * 8192;
    const size_t rowB = (size_t)(b * NPB + hqB * NH) * 8192;

    #pragma unroll
    for (int it = 0; it < 8; ++it) {
        int flat = tid + it * 256;            // 0..2047 ; 1984 used
        if (flat < 1984) {
            int half = (flat >= 992);
            int fl   = flat - (half ? 992 : 0);
            int seg  = fl >> 2;               // 0..247
            int sub  = fl & 3;
            int pw   = seg >> 3;              // 0..30
            int csub = seg & 7;
            const unsigned short* src = ws
                + (half ? rowB : rowA)
                + (size_t)pw * 8192
                + (size_t)(cg * 8 + csub) * 64
                + (half ? 32 : 0)
                + sub * 8;
            int valid = half ? bValid : aValid;
            uint4 val;
            if (valid) {
                val = *(const uint4*)src;
            } else {
                val.x = 0u; val.y = 0u; val.z = 0u; val.w = 0u;
            }
            unsigned short* dst = (half ? sB : sA)
                + (pw + 1) * MSLOT + csub * 32 + sub * 8;
            *(uint4*)dst = val;
        }
    }
    __syncthreads();

    // ---- combine ----
    const int l    = tid & 31;                // w quad : w = 4l..4l+3
    const int csub = tid >> 5;                // 0..7
    const int c    = cg * 8 + csub;

    float* op = out + b * CHW_ + c * HW_ + (hq * 4) * W_ + l * 4;
    #pragma unroll
    for (int hr = 0; hr < 4; ++hr) {
        int baseL = (l + 1) * MSLOT + csub * 32 + hr * 8;
        int baseP = l       * MSLOT + csub * 32 + hr * 8 + 4;
        uint2 aL = *(const uint2*)(sA + baseL);
        uint2 aP = *(const uint2*)(sA + baseP);
        uint2 bL = *(const uint2*)(sB + baseL);
        uint2 bP = *(const uint2*)(sB + baseP);
        float4 r;
        r.x = bflo(aL.x) + bflo(aP.x) + bflo(bL.x) + bflo(bP.x);
        r.y = bfhi(aL.x) + bfhi(aP.x) + bfhi(bL.x) + bfhi(bP.x);
        r.z = bflo(aL.y) + bflo(aP.y) + bflo(bL.y) + bflo(bP.y);
        r.w = bfhi(aL.y) + bfhi(aP.y) + bfhi(bL.y) + bfhi(bP.y);
        *(float4*)(op + hr * W_) = r;
    }
}

// ========================= FALLBACK (atomic) ==============================

__global__ __launch_bounds__(512, 6)
void patch_attn_atomic(const float* __restrict__ q,
                       const float* __restrict__ k,
                       const float* __restrict__ v,
                       float* __restrict__ out)
{
    __shared__ __align__(16) unsigned char lds[43264];
    unsigned short* sQ   = (unsigned short*)(lds);
    unsigned short* sK   = (unsigned short*)(lds + 16384);
    unsigned short* sVT  = (unsigned short*)(lds);
    unsigned short* sP   = (unsigned short*)(lds + 32768);
    float*          sRedM= (float*)(lds + 40960);
    float*          sRedL= (float*)(lds + 41984);
    float*          sInv = (float*)(lds + 43008);

    const int tid  = threadIdx.x;
    const int lane = tid & 63;
    const int wid  = tid >> 6;
    const int l15  = lane & 15;
    const int quad = lane >> 4;

    const int p   = (blockIdx.x & 7) * NPB + (blockIdx.x >> 3);
    const int b   = p / NPB;
    const int rem = p - b * NPB;
    const int ph  = rem / NH;
    const int pw  = rem - ph * NH;
    const int h0  = ph * 4, w0 = pw * 4;
    const int baseB = b * CHW_;

    float4 rq[4], rk[4], rv[4];
    int cA[4], tA[4];
    #pragma unroll
    for (int g = 0; g < 4; ++g) {
        int flat4 = tid + g * 512;
        int jj = flat4 & 1;
        int i  = (flat4 >> 1) & 7;
        int c  = flat4 >> 4;
        int off = baseB + c * HW_ + (h0 + i) * W_ + (w0 + jj * 4);
        rq[g] = *(const float4*)(q + off);
        rk[g] = *(const float4*)(k + off);
        rv[g] = *(const float4*)(v + off);
        cA[g] = c;
        tA[g] = i * 8 + jj * 4;
    }
    #pragma unroll
    for (int g = 0; g < 4; ++g) {
        const float* fq = (const float*)&rq[g];
        const float* fk = (const float*)&rk[g];
        int c = cA[g];
        #pragma unroll
        for (int d = 0; d < 4; ++d) {
            int t = tA[g] + d;
            int idx = t * 128 + ((((c >> 3) ^ (t & 15)) << 3) | (c & 7));
            sQ[idx] = f2bf(fq[d]);
            sK[idx] = f2bf(fk[d]);
        }
    }
    __syncthreads();

    const float scale = 0.08838834764831845f;
    const int nt  = wid & 3;
    const int mt0 = wid >> 2;

    v4f accT[2];
    #pragma unroll
    for (int ti = 0; ti < 2; ++ti) {
        int mt = mt0 + ti * 2;
        v4f acc = {0.f, 0.f, 0.f, 0.f};
        int rowA = mt * 16 + l15;
        int rowB = nt * 16 + l15;
        #pragma unroll
        for (int kk = 0; kk < 4; ++kk) {
            int gph = (kk * 4 + quad) ^ l15;
            v8s a  = *(const v8s*)(&sQ[rowA * 128 + gph * 8]);
            v8s bb = *(const v8s*)(&sK[rowB * 128 + gph * 8]);
            acc = __builtin_amdgcn_mfma_f32_16x16x32_bf16(a, bb, acc, 0, 0, 0);
        }
        #pragma unroll
        for (int r = 0; r < 4; ++r) acc[r] *= scale;
        accT[ti] = acc;
    }

    float4 mloc[2], eV[2];
    #pragma unroll
    for (int ti = 0; ti < 2; ++ti) {
        float4 m;
        #pragma unroll
        for (int r = 0; r < 4; ++r) m[r] = accT[ti][r];
        #pragma unroll
        for (int mask = 1; mask <= 8; mask <<= 1)
            #pragma unroll
            for (int r = 0; r < 4; ++r) m[r] = fmaxf(m[r], __shfl_xor(m[r], mask));
        float4 e, l;
        #pragma unroll
        for (int r = 0; r < 4; ++r) { e[r] = __expf(accT[ti][r] - m[r]); l[r] = e[r]; }
        #pragma unroll
        for (int mask = 1; mask <= 8; mask <<= 1)
            #pragma unroll
            for (int r = 0; r < 4; ++r) l[r] += __shfl_xor(l[r], mask);
        mloc[ti] = m; eV[ti] = e;
        if (l15 == 0) {
            int tb = (mt0 + ti * 2) * 16 + quad * 4;
            #pragma unroll
            for (int r = 0; r < 4; ++r) {
                sRedM[nt * 64 + tb + r] = m[r];
                sRedL[nt * 64 + tb + r] = l[r];
            }
        }
    }
    __syncthreads();

    #pragma unroll
    for (int g = 0; g < 4; ++g) {
        const float* fv = (const float*)&rv[g];
        unsigned short tmp[4];
        #pragma unroll
        for (int d = 0; d < 4; ++d) tmp[d] = f2bf(fv[d]);
        int c = cA[g], s0 = tA[g];
        int idx = c * 64 + ((((s0 >> 3) ^ (c & 7)) << 3) | (s0 & 7));
        *(uint2*)(&sVT[idx]) = *(const uint2*)tmp;
    }

    #pragma unroll
    for (int ti = 0; ti < 2; ++ti) {
        int tb = (mt0 + ti * 2) * 16 + quad * 4;
        float4 Mv[4], Lv[4];
        #pragma unroll
        for (int n2 = 0; n2 < 4; ++n2) {
            Mv[n2] = *(const float4*)(&sRedM[n2 * 64 + tb]);
            Lv[n2] = *(const float4*)(&sRedL[n2 * 64 + tb]);
        }
        float4 M = Mv[0], L;
        #pragma unroll
        for (int n2 = 1; n2 < 4; ++n2)
            #pragma unroll
            for (int r = 0; r < 4; ++r) M[r] = fmaxf(M[r], Mv[n2][r]);
        #pragma unroll
        for (int r = 0; r < 4; ++r) L[r] = 0.f;
        #pragma unroll
        for (int n2 = 0; n2 < 4; ++n2)
            #pragma unroll
            for (int r = 0; r < 4; ++r) L[r] += Lv[n2][r] * __expf(Mv[n2][r] - M[r]);
        #pragma unroll
        for (int r = 0; r < 4; ++r) {
            float pv = eV[ti][r] * __expf(mloc[ti][r] - M[r]);
            int t = tb + r;
            int s = nt * 16 + l15;
            sP[t * 64 + ((((s >> 3) ^ (t & 7)) << 3) | (s & 7))] = f2bf(pv);
        }
        if (nt == 0 && l15 == 0) {
            #pragma unroll
            for (int r = 0; r < 4; ++r) sInv[tb + r] = 1.0f / L[r];
        }
    }
    __syncthreads();

    v4f z[4];
    #pragma unroll
    for (int n2 = 0; n2 < 4; ++n2) z[n2] = (v4f){0.f, 0.f, 0.f, 0.f};
    const int crow = wid * 16 + l15;
    #pragma unroll
    for (int kk = 0; kk < 2; ++kk) {
        int gph = (kk * 4 + quad) ^ (l15 & 7);
        v8s a = *(const v8s*)(&sVT[crow * 64 + gph * 8]);
        #pragma unroll
        for (int n2 = 0; n2 < 4; ++n2) {
            int trow = n2 * 16 + l15;
            v8s bb = *(const v8s*)(&sP[trow * 64 + gph * 8]);
            z[n2] = __builtin_amdgcn_mfma_f32_16x16x32_bf16(a, bb, z[n2], 0, 0, 0);
        }
    }

    #pragma unroll
    for (int n2 = 0; n2 < 4; ++n2) {
        int t = n2 * 16 + l15;
        float inv = sInv[t];
        int base2 = baseB + (h0 + (t >> 3)) * W_ + (w0 + (t & 7));
        #pragma unroll
        for (int r = 0; r < 4; ++r) {
            int c = wid * 16 + quad * 4 + r;
            unsafeAtomicAdd(out + base2 + c * HW_, z[n2][r] * inv);
        }
    }
}

extern "C" void kernel_launch(void* const* d_in, const int* in_sizes, int n_in,
                              void* d_out, int out_size, void* d_ws, size_t ws_size,
                              hipStream_t stream) {
    const float* q = (const float*)d_in[0];
    const float* k = (const float*)d_in[1];
    const float* v = (const float*)d_in[2];
    float* out = (float*)d_out;

    if (ws_size >= WS_BYTES) {
        unsigned short* ws = (unsigned short*)d_ws;
        patch_attn_ws<<<NPAT, 256, 0, stream>>>(q, k, v, ws);
        merge_kernel<<<8 * 32 * 16, 256, 0, stream>>>(ws, out);
    } else {
        hipMemsetAsync(out, 0, (size_t)out_size * sizeof(float), stream);
        patch_attn_atomic<<<NPAT, 512, 0, stream>>>(q, k, v, out);
    }
}